// Round 2
// baseline (197.722 us; speedup 1.0000x reference)
//
#include <hip/hip_runtime.h>
#include <hip/hip_bf16.h>

typedef __attribute__((ext_vector_type(8))) short short8;
typedef __attribute__((ext_vector_type(4))) float f32x4;
typedef unsigned short u16;
typedef __attribute__((ext_vector_type(4))) u16 u16x4;
typedef __attribute__((ext_vector_type(8))) u16 u16x8;

#define LN_EPS 1e-5f
#define NT 384
#define SD 64
#define CH 32
#define CO 128

#define MFMA16(a, b, c) __builtin_amdgcn_mfma_f32_16x16x32_bf16(a, b, c, 0, 0, 0)
// LDS-only barrier: drains lgkm but NOT vmcnt -> global prefetches stay in flight.
#define LDS_BARRIER() asm volatile("s_waitcnt lgkmcnt(0)\n\ts_barrier" ::: "memory")

static __device__ __forceinline__ u16 f2bf(float v) {
    __hip_bfloat16 h = __float2bfloat16(v);
    return *reinterpret_cast<u16*>(&h);
}

// ---------------- Kernel 1: LayerNorm + dual projection + mask ----------------
// Grid 96 = 24 ig x 2 h x 2 sq. Block owns 16 n x 16 s. Projection results are
// transposed through LDS (pst) and written as full-line coalesced stores in
// MFMA fragment order for BOTH a (aws) and b (bts).
__global__ __launch_bounds__(256) void ln_proj_kernel(
    const float* __restrict__ m, const int* __restrict__ mask,
    const float* __restrict__ gamma, const float* __restrict__ beta,
    const float* __restrict__ Wa, const float* __restrict__ Wb,
    u16* __restrict__ aws, u16* __restrict__ bts)
{
    __shared__ float Wl[2][64][33];    // [side][k][c], bank=(k+c)%32 conflict-free
    __shared__ float mn_s[64][260];    // [k][n*16+sl], k-stride 260 -> 8-way max
    __shared__ u16   pst[64 * 264];    // [(side*32+c)][n*16+oct*8+j], stride 264
    __shared__ float mf_s[16][16];     // [sl][n]

    int bid = blockIdx.x;
    int ig = bid >> 2, h = (bid >> 1) & 1, sq = bid & 1;
    int s_base = h * 32 + sq * 16;
    int tid = threadIdx.x;
    int wv = tid >> 6, lane = tid & 63;

    // stage W (transposed into LDS)
    #pragma unroll
    for (int rep = 0; rep < 2; ++rep) {
        int p = rep * 1024 + tid * 4;
        int c = p >> 6, k0 = p & 63;
        float4 va = *(const float4*)(Wa + p);
        float4 vb = *(const float4*)(Wb + p);
        Wl[0][k0 + 0][c] = va.x; Wl[0][k0 + 1][c] = va.y;
        Wl[0][k0 + 2][c] = va.z; Wl[0][k0 + 3][c] = va.w;
        Wl[1][k0 + 0][c] = vb.x; Wl[1][k0 + 1][c] = vb.y;
        Wl[1][k0 + 2][c] = vb.z; Wl[1][k0 + 3][c] = vb.w;
    }
    { // mask tile
        int sl = tid >> 4, n = tid & 15;
        mf_s[sl][n] = (float)mask[(s_base + sl) * NT + ig * 16 + n];
    }

    // LayerNorm: 256 rows, 4 waves x 64 rows, lane = c_in
    float gl = gamma[lane], bl = beta[lane];
    #pragma unroll 2
    for (int it = 0; it < 64; ++it) {
        int r = wv * 64 + it;
        int n = r & 15, sl = r >> 4;
        float x = m[((s_base + sl) * NT + ig * 16 + n) * 64 + lane];
        float v = x;
        #pragma unroll
        for (int off = 1; off < 64; off <<= 1) v += __shfl_xor(v, off);
        float mu = v * (1.0f / 64.0f);
        float d = x - mu;
        float v2 = d * d;
        #pragma unroll
        for (int off = 1; off < 64; off <<= 1) v2 += __shfl_xor(v2, off);
        float rstd = rsqrtf(v2 * (1.0f / 64.0f) + LN_EPS);
        mn_s[lane][n * 16 + sl] = d * rstd * gl + bl;
    }
    __syncthreads();

    // projection: lane = (c, side); wave handles 8 (n, oct) row-units
    {
        int c = tid & 31, side = (tid >> 5) & 1;
        #pragma unroll 2
        for (int uu = 0; uu < 8; ++uu) {
            int u = wv * 8 + uu;
            int n = u >> 1, oct = u & 1;
            float acc[8];
            #pragma unroll
            for (int j = 0; j < 8; ++j) acc[j] = 0.f;
            for (int k = 0; k < 64; ++k) {
                float wk = Wl[side][k][c];
                f32x4 m0 = *(const f32x4*)&mn_s[k][n * 16 + oct * 8];
                f32x4 m1 = *(const f32x4*)&mn_s[k][n * 16 + oct * 8 + 4];
                #pragma unroll
                for (int j = 0; j < 4; ++j) {
                    acc[j]     += m0[j] * wk;
                    acc[4 + j] += m1[j] * wk;
                }
            }
            u16x8 pk;
            #pragma unroll
            for (int j = 0; j < 8; ++j) pk[j] = f2bf(acc[j] * mf_s[oct * 8 + j][n]);
            *(u16x8*)&pst[(side * 32 + c) * 264 + n * 16 + oct * 8] = pk;
        }
    }
    __syncthreads();

    // write-out: 64 regions (32 a-c + 32 b-(n,dh)) x 4 subs, full-line coalesced
    {
        int region = tid >> 2, sub = tid & 3;
        if (region < 32) {
            int cc = region;
            const u16* src = &pst[cc * 264];
            u16* dst = aws + ((cc * 24 + ig) * 2 + h) * 512 + sq * 256;
            #pragma unroll
            for (int r8 = 0; r8 < 8; ++r8) {
                int o = r8 * 32 + sub * 8;
                int q01 = o >> 7, nn = (o >> 3) & 15;
                *(u16x8*)(dst + o) = *(const u16x8*)(src + nn * 16 + q01 * 8);
            }
        } else {
            int rr = region - 32;
            int n = rr >> 1, dh = rr & 1;
            u16* dst = bts + ((ig * 16 + n) * 2 + h) * 1024 + dh * 512 + sq * 256;
            #pragma unroll
            for (int r8 = 0; r8 < 8; ++r8) {
                int o = r8 * 32 + sub * 8;
                int q01 = o >> 7, l15 = (o >> 3) & 15;
                *(u16x8*)(dst + o) =
                    *(const u16x8*)(&pst[(32 + dh * 16 + l15) * 264 + n * 16 + q01 * 8]);
            }
        }
    }
}

// ---------------- Kernel 2: denom + Wo -> per-chunk fragment order ----------------
__global__ __launch_bounds__(384) void prep_kernel(const int* __restrict__ mask,
                                                   float* __restrict__ rdenom,
                                                   const float* __restrict__ wo,
                                                   u16* __restrict__ wos)
{
    int bid = blockIdx.x, tid = threadIdx.x;
    if (bid < NT) {
        int i = bid, j = tid;
        int acc = 0;
        #pragma unroll 8
        for (int s = 0; s < SD; ++s)
            acc += mask[s * NT + i] * mask[s * NT + j];
        rdenom[i * NT + j] = 1.0f / (float)max(acc, 1);
    } else {
        int idx = (bid - NT) * 384 + tid;     // 0..16383
        if (idx < 16384) {
            int c = idx >> 9, g = (idx >> 6) & 7, lane = idx & 63;
            const float* src = wo + (g * 16 + (lane & 15)) * 1024 + c * 32 + (lane >> 4) * 8;
            u16x8 pk;
            #pragma unroll
            for (int j = 0; j < 8; ++j) pk[j] = f2bf(src[j]);
            *(u16x8*)(wos + ((c * 8 + g) * 64 + lane) * 8) = pk;
        }
    }
}

// ---------------- Kernel 3: fused OPM + down-projection ----------------
// Round-0 structure (proven 67.6us): 2 c-chunks per barrier, 4 z-buffers
// (32 KB), 48 MFMA/wave between lgkm-only barriers, wofA/wofB double-buffered.
// Round-2 additions: __launch_bounds__(256,3) to guarantee 3 waves/SIMD
// residency (total regs ~152 <= 512/3, latency-bound kernel needs TLP), and
// T5 s_setprio(1) around the MFMA clusters (phase-split schedule -> scheduler
// can prefer MFMA-entering waves over load-issuing waves).
__global__ __launch_bounds__(256, 3) void opm_kernel(
    const u16* __restrict__ aws,  // [32][24][2][512]   fragment order
    const u16* __restrict__ bts,  // [384][2][2][512]   fragment order
    const u16* __restrict__ wos,  // [32][8][64][8]     fragment order
    const float* __restrict__ rdenom,
    const float* __restrict__ bo,
    float* __restrict__ out)      // [384][384][128]
{
    __shared__ u16 zbuf[4][128 * 32];   // 4 x 8 KB

    int bid = blockIdx.x;
    int ig = bid / 48;
    int jb = bid % 48;
    int tid = threadIdx.x;
    int w = tid >> 6, lane = tid & 63;
    int l15 = lane & 15, quad = lane >> 4;
    int mh = w & 1, nh = w >> 1;
    int swz = (l15 >> 1) & 3;

    // persistent bt fragments (contiguous 1 KB loads from bts)
    short8 btf[4][2];
    #pragma unroll
    for (int mt4 = 0; mt4 < 4; ++mt4) {
        int mt = w * 4 + mt4;
        #pragma unroll
        for (int ks = 0; ks < 2; ++ks)
            btf[mt4][ks] = *(const short8*)(bts +
                ((jb * 8 + (mt >> 1)) * 2 + ks) * 1024 + (mt & 1) * 512 + lane * 8);
    }

    const u16* abase = aws + ig * 1024 + lane * 8;         // + c*24576 + h*512
    const u16* wbase = wos + (nh * 4) * 512 + lane * 8;    // + c*4096 + ni*512

    f32x4 acc[4][4];
    #pragma unroll
    for (int mi = 0; mi < 4; ++mi)
        #pragma unroll
        for (int ni = 0; ni < 4; ++ni)
            acc[mi][ni] = (f32x4){0.f, 0.f, 0.f, 0.f};

    auto loadAf = [&](int c, short8* dst) {
        dst[0] = *(const short8*)(abase + c * 24576);
        dst[1] = *(const short8*)(abase + c * 24576 + 512);
    };
    auto loadWof = [&](int c, short8* dst) {
        #pragma unroll
        for (int ni = 0; ni < 4; ++ni)
            dst[ni] = *(const short8*)(wbase + c * 4096 + ni * 512);
    };
    auto stageA = [&](const short8* a, u16* buf) {
        __builtin_amdgcn_s_setprio(1);
        #pragma unroll
        for (int mt4 = 0; mt4 < 4; ++mt4) {
            f32x4 za = {0.f, 0.f, 0.f, 0.f};
            za = MFMA16(btf[mt4][0], a[0], za);
            za = MFMA16(btf[mt4][1], a[1], za);
            int mt = w * 4 + mt4;
            int row = (mt >> 1) * 16 + l15;
            int chunk = ((mt & 1) * 2 + (quad >> 1)) ^ swz;
            u16x4 pk;
            #pragma unroll
            for (int r = 0; r < 4; ++r) pk[r] = f2bf(za[r]);
            *(u16x4*)((char*)buf + row * 64 + chunk * 16 + (quad & 1) * 8) = pk;
        }
        __builtin_amdgcn_s_setprio(0);
    };
    auto stageB = [&](const u16* buf, const short8* wof) {
        short8 zf[4];
        int chunk = quad ^ swz;
        #pragma unroll
        for (int mi = 0; mi < 4; ++mi) {
            int row = (mh * 4 + mi) * 16 + l15;
            zf[mi] = *(const short8*)((const char*)buf + row * 64 + chunk * 16);
        }
        __builtin_amdgcn_s_setprio(1);
        #pragma unroll
        for (int mi = 0; mi < 4; ++mi)
            #pragma unroll
            for (int ni = 0; ni < 4; ++ni)
                acc[mi][ni] = MFMA16(zf[mi], wof[ni], acc[mi][ni]);
        __builtin_amdgcn_s_setprio(0);
    };

    // ---- prologue ----
    short8 afA[2], afB[2], wofA[4], wofB[4];
    loadAf(0, afA); loadWof(0, wofA);
    loadAf(1, afB); loadWof(1, wofB);
    stageA(afA, zbuf[0]); loadAf(2, afA);
    stageA(afB, zbuf[1]); loadAf(3, afB);
    LDS_BARRIER();

    // ---- main loop: 2 chunks per barrier ----
    for (int t = 0; t < 32; t += 2) {
        if (t + 2 < 32) stageA(afA, zbuf[(t + 2) & 3]);
        loadAf(t + 4 < 32 ? t + 4 : 31, afA);
        if (t + 3 < 32) stageA(afB, zbuf[(t + 3) & 3]);
        loadAf(t + 5 < 32 ? t + 5 : 31, afB);
        stageB(zbuf[t & 3], wofA);
        loadWof(t + 2 < 32 ? t + 2 : 31, wofA);
        stageB(zbuf[(t + 1) & 3], wofB);
        loadWof(t + 3 < 32 ? t + 3 : 31, wofB);
        LDS_BARRIER();
    }

    // ---- epilogue: rdenom, bias, store ----
    float bov[4];
    #pragma unroll
    for (int ni = 0; ni < 4; ++ni) bov[ni] = bo[nh * 64 + ni * 16 + l15];
    #pragma unroll
    for (int mi = 0; mi < 4; ++mi) {
        int j_g = jb * 8 + mh * 4 + mi;
        #pragma unroll
        for (int r = 0; r < 4; ++r) {
            int i_g = ig * 16 + quad * 4 + r;
            float rd = rdenom[i_g * NT + j_g];
            float* orow = out + (i_g * NT + j_g) * CO + nh * 64 + l15;
            #pragma unroll
            for (int ni = 0; ni < 4; ++ni)
                orow[ni * 16] = acc[mi][ni][r] * rd + bov[ni];
        }
    }
}

// ---------------- launch ----------------
extern "C" void kernel_launch(void* const* d_in, const int* in_sizes, int n_in,
                              void* d_out, int out_size, void* d_ws, size_t ws_size,
                              hipStream_t stream) {
    const float* m     = (const float*)d_in[0];
    const int*   mask  = (const int*)d_in[1];
    const float* gamma = (const float*)d_in[2];
    const float* beta  = (const float*)d_in[3];
    const float* Wa    = (const float*)d_in[4];
    const float* Wb    = (const float*)d_in[5];
    const float* Wo    = (const float*)d_in[6];
    const float* bo    = (const float*)d_in[7];
    float* out = (float*)d_out;

    char* ws = (char*)d_ws;
    u16*   aws   = (u16*)(ws);                    // 1.5 MB fragment-order a
    u16*   bts   = (u16*)(ws + 1572864);          // 1.5 MB fragment-order b
    u16*   wos   = (u16*)(ws + 3145728);          // 256 KB fragment-order wo
    float* rden  = (float*)(ws + 3407872);        // 576 KB

    ln_proj_kernel<<<96, 256, 0, stream>>>(m, mask, gamma, beta, Wa, Wb, aws, bts);
    prep_kernel<<<NT + 43, 384, 0, stream>>>(mask, rden, Wo, wos);
    opm_kernel<<<24 * 48, 256, 0, stream>>>(aws, bts, wos, rden, bo, out);
}

// Round 3
// 195.505 us; speedup vs baseline: 1.0113x; 1.0113x over previous
//
#include <hip/hip_runtime.h>
#include <hip/hip_bf16.h>

typedef __attribute__((ext_vector_type(8))) short short8;
typedef __attribute__((ext_vector_type(4))) float f32x4;
typedef unsigned short u16;
typedef __attribute__((ext_vector_type(4))) u16 u16x4;
typedef __attribute__((ext_vector_type(8))) u16 u16x8;

#define LN_EPS 1e-5f
#define NT 384
#define SD 64
#define CH 32
#define CO 128

#define MFMA16(a, b, c) __builtin_amdgcn_mfma_f32_16x16x32_bf16(a, b, c, 0, 0, 0)
// LDS-only barrier: drains lgkm but NOT vmcnt -> global prefetches stay in flight.
#define LDS_BARRIER() asm volatile("s_waitcnt lgkmcnt(0)\n\ts_barrier" ::: "memory")

static __device__ __forceinline__ u16 f2bf(float v) {
    __hip_bfloat16 h = __float2bfloat16(v);
    return *reinterpret_cast<u16*>(&h);
}

// ---------------- Kernel 1: LayerNorm + dual projection + mask ----------------
// Grid 96 = 24 ig x 2 h x 2 sq. Block owns 16 n x 16 s. Projection results are
// transposed through LDS (pst) and written as full-line coalesced stores in
// MFMA fragment order for BOTH a (aws) and b (bts).
__global__ __launch_bounds__(256) void ln_proj_kernel(
    const float* __restrict__ m, const int* __restrict__ mask,
    const float* __restrict__ gamma, const float* __restrict__ beta,
    const float* __restrict__ Wa, const float* __restrict__ Wb,
    u16* __restrict__ aws, u16* __restrict__ bts)
{
    __shared__ float Wl[2][64][33];    // [side][k][c], bank=(k+c)%32 conflict-free
    __shared__ float mn_s[64][260];    // [k][n*16+sl], k-stride 260 -> 8-way max
    __shared__ u16   pst[64 * 264];    // [(side*32+c)][n*16+oct*8+j], stride 264
    __shared__ float mf_s[16][16];     // [sl][n]

    int bid = blockIdx.x;
    int ig = bid >> 2, h = (bid >> 1) & 1, sq = bid & 1;
    int s_base = h * 32 + sq * 16;
    int tid = threadIdx.x;
    int wv = tid >> 6, lane = tid & 63;

    // stage W (transposed into LDS)
    #pragma unroll
    for (int rep = 0; rep < 2; ++rep) {
        int p = rep * 1024 + tid * 4;
        int c = p >> 6, k0 = p & 63;
        float4 va = *(const float4*)(Wa + p);
        float4 vb = *(const float4*)(Wb + p);
        Wl[0][k0 + 0][c] = va.x; Wl[0][k0 + 1][c] = va.y;
        Wl[0][k0 + 2][c] = va.z; Wl[0][k0 + 3][c] = va.w;
        Wl[1][k0 + 0][c] = vb.x; Wl[1][k0 + 1][c] = vb.y;
        Wl[1][k0 + 2][c] = vb.z; Wl[1][k0 + 3][c] = vb.w;
    }
    { // mask tile
        int sl = tid >> 4, n = tid & 15;
        mf_s[sl][n] = (float)mask[(s_base + sl) * NT + ig * 16 + n];
    }

    // LayerNorm: 256 rows, 4 waves x 64 rows, lane = c_in
    float gl = gamma[lane], bl = beta[lane];
    #pragma unroll 2
    for (int it = 0; it < 64; ++it) {
        int r = wv * 64 + it;
        int n = r & 15, sl = r >> 4;
        float x = m[((s_base + sl) * NT + ig * 16 + n) * 64 + lane];
        float v = x;
        #pragma unroll
        for (int off = 1; off < 64; off <<= 1) v += __shfl_xor(v, off);
        float mu = v * (1.0f / 64.0f);
        float d = x - mu;
        float v2 = d * d;
        #pragma unroll
        for (int off = 1; off < 64; off <<= 1) v2 += __shfl_xor(v2, off);
        float rstd = rsqrtf(v2 * (1.0f / 64.0f) + LN_EPS);
        mn_s[lane][n * 16 + sl] = d * rstd * gl + bl;
    }
    __syncthreads();

    // projection: lane = (c, side); wave handles 8 (n, oct) row-units
    {
        int c = tid & 31, side = (tid >> 5) & 1;
        #pragma unroll 2
        for (int uu = 0; uu < 8; ++uu) {
            int u = wv * 8 + uu;
            int n = u >> 1, oct = u & 1;
            float acc[8];
            #pragma unroll
            for (int j = 0; j < 8; ++j) acc[j] = 0.f;
            for (int k = 0; k < 64; ++k) {
                float wk = Wl[side][k][c];
                f32x4 m0 = *(const f32x4*)&mn_s[k][n * 16 + oct * 8];
                f32x4 m1 = *(const f32x4*)&mn_s[k][n * 16 + oct * 8 + 4];
                #pragma unroll
                for (int j = 0; j < 4; ++j) {
                    acc[j]     += m0[j] * wk;
                    acc[4 + j] += m1[j] * wk;
                }
            }
            u16x8 pk;
            #pragma unroll
            for (int j = 0; j < 8; ++j) pk[j] = f2bf(acc[j] * mf_s[oct * 8 + j][n]);
            *(u16x8*)&pst[(side * 32 + c) * 264 + n * 16 + oct * 8] = pk;
        }
    }
    __syncthreads();

    // write-out: 64 regions (32 a-c + 32 b-(n,dh)) x 4 subs, full-line coalesced
    {
        int region = tid >> 2, sub = tid & 3;
        if (region < 32) {
            int cc = region;
            const u16* src = &pst[cc * 264];
            u16* dst = aws + ((cc * 24 + ig) * 2 + h) * 512 + sq * 256;
            #pragma unroll
            for (int r8 = 0; r8 < 8; ++r8) {
                int o = r8 * 32 + sub * 8;
                int q01 = o >> 7, nn = (o >> 3) & 15;
                *(u16x8*)(dst + o) = *(const u16x8*)(src + nn * 16 + q01 * 8);
            }
        } else {
            int rr = region - 32;
            int n = rr >> 1, dh = rr & 1;
            u16* dst = bts + ((ig * 16 + n) * 2 + h) * 1024 + dh * 512 + sq * 256;
            #pragma unroll
            for (int r8 = 0; r8 < 8; ++r8) {
                int o = r8 * 32 + sub * 8;
                int q01 = o >> 7, l15 = (o >> 3) & 15;
                *(u16x8*)(dst + o) =
                    *(const u16x8*)(&pst[(32 + dh * 16 + l15) * 264 + n * 16 + q01 * 8]);
            }
        }
    }
}

// ---------------- Kernel 2: denom + Wo -> per-chunk fragment order ----------------
__global__ __launch_bounds__(384) void prep_kernel(const int* __restrict__ mask,
                                                   float* __restrict__ rdenom,
                                                   const float* __restrict__ wo,
                                                   u16* __restrict__ wos)
{
    int bid = blockIdx.x, tid = threadIdx.x;
    if (bid < NT) {
        int i = bid, j = tid;
        int acc = 0;
        #pragma unroll 8
        for (int s = 0; s < SD; ++s)
            acc += mask[s * NT + i] * mask[s * NT + j];
        rdenom[i * NT + j] = 1.0f / (float)max(acc, 1);
    } else {
        int idx = (bid - NT) * 384 + tid;     // 0..16383
        if (idx < 16384) {
            int c = idx >> 9, g = (idx >> 6) & 7, lane = idx & 63;
            const float* src = wo + (g * 16 + (lane & 15)) * 1024 + c * 32 + (lane >> 4) * 8;
            u16x8 pk;
            #pragma unroll
            for (int j = 0; j < 8; ++j) pk[j] = f2bf(src[j]);
            *(u16x8*)(wos + ((c * 8 + g) * 64 + lane) * 8) = pk;
        }
    }
}

// ---------------- Kernel 3: fused OPM + down-projection (j-split tiles) ----------------
// Round-0 proven schedule (2 chunks/barrier, lgkm-only barriers, wofA/wofB
// double-buffered), but tile = 16i x 4j x 128o -> grid 24 x 96 = 2304 blocks.
// Rationale: 1152 blocks on 512 (2-res) or 768 (3-res) slots = 2.25 / 1.5
// blocks per slot -> integer-assignment tail idles ~25% of the grid. 2304
// blocks at EXACTLY 3 resident blocks/CU = 768 slots x 3 rounds = perfect
// packing. Residency pinned to 3 via 48 KB LDS (12 x 4 KB zbuf slots, 4 used;
// 160/48 = 3.33 -> 3). j-split duplicates zero FLOPs (stageA and stageB both
// halve; MFMA tiles stay fully utilized).
__global__ __launch_bounds__(256, 2) void opm_kernel(
    const u16* __restrict__ aws,  // [32][24][2][512]   fragment order
    const u16* __restrict__ bts,  // [384][2][2][512]   fragment order
    const u16* __restrict__ wos,  // [32][8][64][8]     fragment order
    const float* __restrict__ rdenom,
    const float* __restrict__ bo,
    float* __restrict__ out)      // [384][384][128]
{
    // 12 slots x 4 KB = 48 KB; only slots 0..3 are used (rotation & 3). The
    // oversize is deliberate: it pins occupancy to exactly 3 blocks/CU.
    __shared__ u16 zbuf[12][64 * 32];

    int bid = blockIdx.x;
    int ig = bid / 96;
    int jb = bid % 96;
    int tid = threadIdx.x;
    int w = tid >> 6, lane = tid & 63;
    int l15 = lane & 15, quad = lane >> 4;
    int jq = w & 1, nh = w >> 1;
    int swz = (l15 >> 1) & 3;

    // b fragments for this wave's produced j (j_local = w): [dh][ks]
    short8 btf[2][2];
    #pragma unroll
    for (int dh = 0; dh < 2; ++dh)
        #pragma unroll
        for (int ks = 0; ks < 2; ++ks)
            btf[dh][ks] = *(const short8*)(bts +
                ((jb * 4 + w) * 2 + ks) * 1024 + dh * 512 + lane * 8);

    const u16* abase = aws + ig * 1024 + lane * 8;         // + c*24576 (+512 ks=1)
    const u16* wbase = wos + (nh * 4) * 512 + lane * 8;    // + c*4096 + ni*512

    f32x4 acc[2][4];
    #pragma unroll
    for (int jj = 0; jj < 2; ++jj)
        #pragma unroll
        for (int ni = 0; ni < 4; ++ni)
            acc[jj][ni] = (f32x4){0.f, 0.f, 0.f, 0.f};

    auto loadAf = [&](int c, short8* dst) {
        dst[0] = *(const short8*)(abase + c * 24576);
        dst[1] = *(const short8*)(abase + c * 24576 + 512);
    };
    auto loadWof = [&](int c, short8* dst) {
        #pragma unroll
        for (int ni = 0; ni < 4; ++ni)
            dst[ni] = *(const short8*)(wbase + c * 4096 + ni * 512);
    };
    // z tile per chunk: rows (j_local*16 + i) x 32 d, 64 B/row, XOR-swizzled in
    // 16 B chunks by swz(i). Wave w produces j_local = w (rows [16w, 16w+16)).
    auto stageA = [&](const short8* a, u16* buf) {
        #pragma unroll
        for (int dh = 0; dh < 2; ++dh) {
            f32x4 za = {0.f, 0.f, 0.f, 0.f};
            za = MFMA16(btf[dh][0], a[0], za);
            za = MFMA16(btf[dh][1], a[1], za);
            int row = w * 16 + l15;
            int chunk = (dh * 2 + (quad >> 1)) ^ swz;
            u16x4 pk;
            #pragma unroll
            for (int r = 0; r < 4; ++r) pk[r] = f2bf(za[r]);
            *(u16x4*)((char*)buf + row * 64 + chunk * 16 + (quad & 1) * 8) = pk;
        }
    };
    // wave (jq, nh) consumes j_local in {2jq, 2jq+1}, o-half nh
    auto stageB = [&](const u16* buf, const short8* wof) {
        short8 zf[2];
        int chunk = quad ^ swz;
        #pragma unroll
        for (int jj = 0; jj < 2; ++jj) {
            int row = (jq * 2 + jj) * 16 + l15;
            zf[jj] = *(const short8*)((const char*)buf + row * 64 + chunk * 16);
        }
        #pragma unroll
        for (int jj = 0; jj < 2; ++jj)
            #pragma unroll
            for (int ni = 0; ni < 4; ++ni)
                acc[jj][ni] = MFMA16(zf[jj], wof[ni], acc[jj][ni]);
    };

    // ---- prologue ----
    short8 afA[2], afB[2], wofA[4], wofB[4];
    loadAf(0, afA); loadWof(0, wofA);
    loadAf(1, afB); loadWof(1, wofB);
    stageA(afA, zbuf[0]); loadAf(2, afA);
    stageA(afB, zbuf[1]); loadAf(3, afB);
    LDS_BARRIER();

    // ---- main loop: 2 chunks per barrier ----
    for (int t = 0; t < 32; t += 2) {
        if (t + 2 < 32) stageA(afA, zbuf[(t + 2) & 3]);
        loadAf(t + 4 < 32 ? t + 4 : 31, afA);
        if (t + 3 < 32) stageA(afB, zbuf[(t + 3) & 3]);
        loadAf(t + 5 < 32 ? t + 5 : 31, afB);
        stageB(zbuf[t & 3], wofA);
        loadWof(t + 2 < 32 ? t + 2 : 31, wofA);
        stageB(zbuf[(t + 1) & 3], wofB);
        loadWof(t + 3 < 32 ? t + 3 : 31, wofB);
        LDS_BARRIER();
    }

    // ---- epilogue: rdenom, bias, store ----
    float bov[4];
    #pragma unroll
    for (int ni = 0; ni < 4; ++ni) bov[ni] = bo[nh * 64 + ni * 16 + l15];
    #pragma unroll
    for (int jj = 0; jj < 2; ++jj) {
        int j_g = jb * 4 + jq * 2 + jj;
        #pragma unroll
        for (int r = 0; r < 4; ++r) {
            int i_g = ig * 16 + quad * 4 + r;
            float rd = rdenom[i_g * NT + j_g];
            float* orow = out + (i_g * NT + j_g) * CO + nh * 64 + l15;
            #pragma unroll
            for (int ni = 0; ni < 4; ++ni)
                orow[ni * 16] = acc[jj][ni][r] * rd + bov[ni];
        }
    }
}

// ---------------- launch ----------------
extern "C" void kernel_launch(void* const* d_in, const int* in_sizes, int n_in,
                              void* d_out, int out_size, void* d_ws, size_t ws_size,
                              hipStream_t stream) {
    const float* m     = (const float*)d_in[0];
    const int*   mask  = (const int*)d_in[1];
    const float* gamma = (const float*)d_in[2];
    const float* beta  = (const float*)d_in[3];
    const float* Wa    = (const float*)d_in[4];
    const float* Wb    = (const float*)d_in[5];
    const float* Wo    = (const float*)d_in[6];
    const float* bo    = (const float*)d_in[7];
    float* out = (float*)d_out;

    char* ws = (char*)d_ws;
    u16*   aws   = (u16*)(ws);                    // 1.5 MB fragment-order a
    u16*   bts   = (u16*)(ws + 1572864);          // 1.5 MB fragment-order b
    u16*   wos   = (u16*)(ws + 3145728);          // 256 KB fragment-order wo
    float* rden  = (float*)(ws + 3407872);        // 576 KB

    ln_proj_kernel<<<96, 256, 0, stream>>>(m, mask, gamma, beta, Wa, Wb, aws, bts);
    prep_kernel<<<NT + 43, 384, 0, stream>>>(mask, rden, Wo, wos);
    opm_kernel<<<24 * 96, 256, 0, stream>>>(aws, bts, wos, rden, bo, out);
}

// Round 4
// 151.265 us; speedup vs baseline: 1.3071x; 1.2925x over previous
//
#include <hip/hip_runtime.h>
#include <hip/hip_bf16.h>

typedef __attribute__((ext_vector_type(8))) short short8;
typedef __attribute__((ext_vector_type(4))) float f32x4;
typedef unsigned short u16;
typedef __attribute__((ext_vector_type(4))) u16 u16x4;
typedef __attribute__((ext_vector_type(8))) u16 u16x8;

#define LN_EPS 1e-5f
#define NT 384
#define SD 64
#define CH 32
#define CO 128

#define MFMA16(a, b, c) __builtin_amdgcn_mfma_f32_16x16x32_bf16(a, b, c, 0, 0, 0)
// LDS-only barrier: drains lgkm but NOT vmcnt -> global prefetches stay in flight.
#define LDS_BARRIER() asm volatile("s_waitcnt lgkmcnt(0)\n\ts_barrier" ::: "memory")

static __device__ __forceinline__ u16 f2bf(float v) {
    __hip_bfloat16 h = __float2bfloat16(v);
    return *reinterpret_cast<u16*>(&h);
}

// ---------------- Kernel 1: LN + dual projection (MFMA) + prep, fused ----------------
// Blocks 0..95: ln_proj tile (24 ig x 2 h x 2 sq), 16n x 16s.
//   LN: 16-lane groups, float4 per lane, 4 rows/wave-iter (16 iters vs old 64;
//       8 shuffle levels vs 12). mn stored bf16 in LDS [col][72-pad].
//   Projection: MFMA 16x16x32 — wave = one 16-channel tile of W' (Wa rows for
//   wv 0,1; Wb rows for wv 2,3), 16 row-tiles x 2 kMFMA = 32 MFMA/wave.
//   Replaces ~4096 VALU FMA + 1536 LDS instr/wave. pst layout byte-identical
//   to the previous kernel -> write-out phase unchanged.
// Blocks 96..671: rdenom (147456 pairs / 256).
// Blocks 672..735: Wo repack to fragment order.
__global__ __launch_bounds__(256) void ln_prep_kernel(
    const float* __restrict__ m, const int* __restrict__ mask,
    const float* __restrict__ gamma, const float* __restrict__ beta,
    const float* __restrict__ Wa, const float* __restrict__ Wb,
    const float* __restrict__ wo, const float* __restrict__ unused_bo,
    u16* __restrict__ aws, u16* __restrict__ bts,
    float* __restrict__ rdenom, u16* __restrict__ wos)
{
    __shared__ u16   mn_s[256 * 72];   // [col=n*16+sl][k], 72-pad -> balanced banks
    __shared__ u16   pst[64 * 264];    // [(side*32+c)][n*16+oct*8+j], stride 264
    __shared__ float mf_s[16][16];     // [sl][n]

    int bid = blockIdx.x;
    int tid = threadIdx.x;

    if (bid >= 96) {
        if (bid < 672) {               // ---- rdenom ----
            int flat = (bid - 96) * 256 + tid;   // < 147456
            int i = flat / NT, j = flat - i * NT;
            int acc = 0;
            #pragma unroll 8
            for (int s = 0; s < SD; ++s)
                acc += mask[s * NT + i] * mask[s * NT + j];
            rdenom[i * NT + j] = 1.0f / (float)max(acc, 1);
        } else {                       // ---- Wo repack ----
            int idx = (bid - 672) * 256 + tid;   // < 16384
            int c = idx >> 9, g = (idx >> 6) & 7, lane = idx & 63;
            const float* src = wo + (g * 16 + (lane & 15)) * 1024 + c * 32 + (lane >> 4) * 8;
            u16x8 pk;
            #pragma unroll
            for (int j = 0; j < 8; ++j) pk[j] = f2bf(src[j]);
            *(u16x8*)(wos + ((c * 8 + g) * 64 + lane) * 8) = pk;
        }
        return;
    }

    // ---------------- ln_proj path ----------------
    int ig = bid >> 2, h = (bid >> 1) & 1, sq = bid & 1;
    int s_base = h * 32 + sq * 16;
    int wv = tid >> 6, lane = tid & 63;
    int l15 = lane & 15, quad = lane >> 4;

    { // mask tile
        int sl = tid >> 4, n = tid & 15;
        mf_s[sl][n] = (float)mask[(s_base + sl) * NT + ig * 16 + n];
    }

    // W fragments (registers, once): wave wv owns channels [wv*16, wv*16+16)
    // of W' = [Wa; Wb]. A-frag: row = l15 (channel), k = quad*8 + e.
    const float* Wsrc = (wv < 2) ? Wa : Wb;
    int wrow = (wv & 1) * 16 + l15;
    short8 wfrag[2];
    #pragma unroll
    for (int ks = 0; ks < 2; ++ks) {
        float4 w0 = *(const float4*)(Wsrc + wrow * 64 + ks * 32 + quad * 8);
        float4 w1 = *(const float4*)(Wsrc + wrow * 64 + ks * 32 + quad * 8 + 4);
        u16x8 wp;
        wp[0] = f2bf(w0.x); wp[1] = f2bf(w0.y); wp[2] = f2bf(w0.z); wp[3] = f2bf(w0.w);
        wp[4] = f2bf(w1.x); wp[5] = f2bf(w1.y); wp[6] = f2bf(w1.z); wp[7] = f2bf(w1.w);
        wfrag[ks] = *reinterpret_cast<short8*>(&wp);
    }

    // LayerNorm: 16-lane groups, lane holds 4 c (float4); 4 rows per wave-iter.
    {
        int g = quad;                  // row-within-group
        int c4 = l15 * 4;
        float4 gl = *(const float4*)(gamma + c4);
        float4 bl = *(const float4*)(beta + c4);
        #pragma unroll 4
        for (int it = 0; it < 16; ++it) {
            int r = wv * 64 + it * 4 + g;
            int n = r & 15, sl = r >> 4;
            float4 x = *(const float4*)(m + (((s_base + sl) * NT + ig * 16 + n) << 6) + c4);
            float v = (x.x + x.y) + (x.z + x.w);
            v += __shfl_xor(v, 1); v += __shfl_xor(v, 2);
            v += __shfl_xor(v, 4); v += __shfl_xor(v, 8);
            float mu = v * (1.0f / 64.0f);
            float dx = x.x - mu, dy = x.y - mu, dz = x.z - mu, dw = x.w - mu;
            float v2 = (dx * dx + dy * dy) + (dz * dz + dw * dw);
            v2 += __shfl_xor(v2, 1); v2 += __shfl_xor(v2, 2);
            v2 += __shfl_xor(v2, 4); v2 += __shfl_xor(v2, 8);
            float rstd = rsqrtf(v2 * (1.0f / 64.0f) + LN_EPS);
            u16x4 pk;
            pk[0] = f2bf(dx * rstd * gl.x + bl.x);
            pk[1] = f2bf(dy * rstd * gl.y + bl.y);
            pk[2] = f2bf(dz * rstd * gl.z + bl.z);
            pk[3] = f2bf(dw * rstd * gl.w + bl.w);
            *(u16x4*)&mn_s[(n * 16 + sl) * 72 + c4] = pk;
        }
    }
    __syncthreads();

    // Projection: D[ch][col] = W'[ch][k] * mn[col][k], 16 col-tiles x 2 kMFMA.
    // C/D: col = l15 (= row-index n*16+sl), row = quad*4+reg (= ch within tile).
    {
        #pragma unroll 4
        for (int rt = 0; rt < 16; ++rt) {
            short8 b0 = *(const short8*)&mn_s[(rt * 16 + l15) * 72 + quad * 8];
            short8 b1 = *(const short8*)&mn_s[(rt * 16 + l15) * 72 + 32 + quad * 8];
            f32x4 d = (f32x4){0.f, 0.f, 0.f, 0.f};
            d = MFMA16(wfrag[0], b0, d);
            d = MFMA16(wfrag[1], b1, d);
            float mval = mf_s[l15][rt];   // sl = l15, n = rt
            #pragma unroll
            for (int r = 0; r < 4; ++r)
                pst[(wv * 16 + quad * 4 + r) * 264 + rt * 16 + l15] = f2bf(d[r] * mval);
        }
    }
    __syncthreads();

    // write-out: 64 regions (32 a-c + 32 b-(n,dh)) x 4 subs, full-line coalesced
    {
        int region = tid >> 2, sub = tid & 3;
        if (region < 32) {
            int cc = region;
            const u16* src = &pst[cc * 264];
            u16* dst = aws + ((cc * 24 + ig) * 2 + h) * 512 + sq * 256;
            #pragma unroll
            for (int r8 = 0; r8 < 8; ++r8) {
                int o = r8 * 32 + sub * 8;
                int q01 = o >> 7, nn = (o >> 3) & 15;
                *(u16x8*)(dst + o) = *(const u16x8*)(src + nn * 16 + q01 * 8);
            }
        } else {
            int rr = region - 32;
            int n = rr >> 1, dh = rr & 1;
            u16* dst = bts + ((ig * 16 + n) * 2 + h) * 1024 + dh * 512 + sq * 256;
            #pragma unroll
            for (int r8 = 0; r8 < 8; ++r8) {
                int o = r8 * 32 + sub * 8;
                int q01 = o >> 7, l15b = (o >> 3) & 15;
                *(u16x8*)(dst + o) =
                    *(const u16x8*)(&pst[(32 + dh * 16 + l15b) * 264 + n * 16 + q01 * 8]);
            }
        }
    }
}

// ---------------- Kernel 2: fused OPM + down-projection (round-0, proven) ----------------
// 2 c-chunks per barrier, 4 z-buffers (32 KB). 48 MFMA/wave between barriers.
__global__ __launch_bounds__(256, 2) void opm_kernel(
    const u16* __restrict__ aws,  // [32][24][2][512]   fragment order
    const u16* __restrict__ bts,  // [384][2][2][512]   fragment order
    const u16* __restrict__ wos,  // [32][8][64][8]     fragment order
    const float* __restrict__ rdenom,
    const float* __restrict__ bo,
    float* __restrict__ out)      // [384][384][128]
{
    __shared__ u16 zbuf[4][128 * 32];   // 4 x 8 KB

    int bid = blockIdx.x;
    int ig = bid / 48;
    int jb = bid % 48;
    int tid = threadIdx.x;
    int w = tid >> 6, lane = tid & 63;
    int l15 = lane & 15, quad = lane >> 4;
    int mh = w & 1, nh = w >> 1;
    int swz = (l15 >> 1) & 3;

    // persistent bt fragments (contiguous 1 KB loads from bts)
    short8 btf[4][2];
    #pragma unroll
    for (int mt4 = 0; mt4 < 4; ++mt4) {
        int mt = w * 4 + mt4;
        #pragma unroll
        for (int ks = 0; ks < 2; ++ks)
            btf[mt4][ks] = *(const short8*)(bts +
                ((jb * 8 + (mt >> 1)) * 2 + ks) * 1024 + (mt & 1) * 512 + lane * 8);
    }

    const u16* abase = aws + ig * 1024 + lane * 8;         // + c*24576 + h*512
    const u16* wbase = wos + (nh * 4) * 512 + lane * 8;    // + c*4096 + ni*512

    f32x4 acc[4][4];
    #pragma unroll
    for (int mi = 0; mi < 4; ++mi)
        #pragma unroll
        for (int ni = 0; ni < 4; ++ni)
            acc[mi][ni] = (f32x4){0.f, 0.f, 0.f, 0.f};

    auto loadAf = [&](int c, short8* dst) {
        dst[0] = *(const short8*)(abase + c * 24576);
        dst[1] = *(const short8*)(abase + c * 24576 + 512);
    };
    auto loadWof = [&](int c, short8* dst) {
        #pragma unroll
        for (int ni = 0; ni < 4; ++ni)
            dst[ni] = *(const short8*)(wbase + c * 4096 + ni * 512);
    };
    auto stageA = [&](const short8* a, u16* buf) {
        #pragma unroll
        for (int mt4 = 0; mt4 < 4; ++mt4) {
            f32x4 za = {0.f, 0.f, 0.f, 0.f};
            za = MFMA16(btf[mt4][0], a[0], za);
            za = MFMA16(btf[mt4][1], a[1], za);
            int mt = w * 4 + mt4;
            int row = (mt >> 1) * 16 + l15;
            int chunk = ((mt & 1) * 2 + (quad >> 1)) ^ swz;
            u16x4 pk;
            #pragma unroll
            for (int r = 0; r < 4; ++r) pk[r] = f2bf(za[r]);
            *(u16x4*)((char*)buf + row * 64 + chunk * 16 + (quad & 1) * 8) = pk;
        }
    };
    auto stageB = [&](const u16* buf, const short8* wof) {
        short8 zf[4];
        int chunk = quad ^ swz;
        #pragma unroll
        for (int mi = 0; mi < 4; ++mi) {
            int row = (mh * 4 + mi) * 16 + l15;
            zf[mi] = *(const short8*)((const char*)buf + row * 64 + chunk * 16);
        }
        #pragma unroll
        for (int mi = 0; mi < 4; ++mi)
            #pragma unroll
            for (int ni = 0; ni < 4; ++ni)
                acc[mi][ni] = MFMA16(zf[mi], wof[ni], acc[mi][ni]);
    };

    // ---- prologue ----
    short8 afA[2], afB[2], wofA[4], wofB[4];
    loadAf(0, afA); loadWof(0, wofA);
    loadAf(1, afB); loadWof(1, wofB);
    stageA(afA, zbuf[0]); loadAf(2, afA);
    stageA(afB, zbuf[1]); loadAf(3, afB);
    LDS_BARRIER();

    // ---- main loop: 2 chunks per barrier ----
    for (int t = 0; t < 32; t += 2) {
        if (t + 2 < 32) stageA(afA, zbuf[(t + 2) & 3]);
        loadAf(t + 4 < 32 ? t + 4 : 31, afA);
        if (t + 3 < 32) stageA(afB, zbuf[(t + 3) & 3]);
        loadAf(t + 5 < 32 ? t + 5 : 31, afB);
        stageB(zbuf[t & 3], wofA);
        loadWof(t + 2 < 32 ? t + 2 : 31, wofA);
        stageB(zbuf[(t + 1) & 3], wofB);
        loadWof(t + 3 < 32 ? t + 3 : 31, wofB);
        LDS_BARRIER();
    }

    // ---- epilogue: rdenom, bias, store ----
    float bov[4];
    #pragma unroll
    for (int ni = 0; ni < 4; ++ni) bov[ni] = bo[nh * 64 + ni * 16 + l15];
    #pragma unroll
    for (int mi = 0; mi < 4; ++mi) {
        int j_g = jb * 8 + mh * 4 + mi;
        #pragma unroll
        for (int r = 0; r < 4; ++r) {
            int i_g = ig * 16 + quad * 4 + r;
            float rd = rdenom[i_g * NT + j_g];
            float* orow = out + (i_g * NT + j_g) * CO + nh * 64 + l15;
            #pragma unroll
            for (int ni = 0; ni < 4; ++ni)
                orow[ni * 16] = acc[mi][ni][r] * rd + bov[ni];
        }
    }
}

// ---------------- launch ----------------
extern "C" void kernel_launch(void* const* d_in, const int* in_sizes, int n_in,
                              void* d_out, int out_size, void* d_ws, size_t ws_size,
                              hipStream_t stream) {
    const float* m     = (const float*)d_in[0];
    const int*   mask  = (const int*)d_in[1];
    const float* gamma = (const float*)d_in[2];
    const float* beta  = (const float*)d_in[3];
    const float* Wa    = (const float*)d_in[4];
    const float* Wb    = (const float*)d_in[5];
    const float* Wo    = (const float*)d_in[6];
    const float* bo    = (const float*)d_in[7];
    float* out = (float*)d_out;

    char* ws = (char*)d_ws;
    u16*   aws   = (u16*)(ws);                    // 1.5 MB fragment-order a
    u16*   bts   = (u16*)(ws + 1572864);          // 1.5 MB fragment-order b
    u16*   wos   = (u16*)(ws + 3145728);          // 256 KB fragment-order wo
    float* rden  = (float*)(ws + 3407872);        // 576 KB

    ln_prep_kernel<<<736, 256, 0, stream>>>(m, mask, gamma, beta, Wa, Wb, Wo, bo,
                                            aws, bts, rden, wos);
    opm_kernel<<<24 * 48, 256, 0, stream>>>(aws, bts, wos, rden, bo, out);
}